// Round 18
// baseline (307.333 us; speedup 1.0000x reference)
//
#include <hip/hip_runtime.h>

#define NN     50000
#define NRELB  20
#define RR     (2*NRELB + 1)      // 41
#define NHID   16
#define NCLASS 50
#define EB     1600000
#define RH     (RR * NHID)        // 656
#define STRIDE 128                // per-node bucket capacity (max deg+1 ~ 105)
#define KPAD   672                // 656 padded to 21*32
#define APAD   680                // afL row stride (elems)
#define NKB    21                 // K-blocks of 32 in the gemm
#define NCT    4                  // class tiles of 16 (64 >= 50)
#define NROWS  50048              // 3128*16 node rows (padded)
#define PM     72                 // padded k-stride (elems) for rT
#define AGW    4                  // waves (= nodes) per block (layer1)
#define FNPB   16                 // nodes per block (fused agg+gemm)
#define FW     8                  // waves per block (fused agg+gemm)

#define NBIN   391                // node-range bins (128 nodes each, s>>7)
#define BINCAP 12288              // records per bin (mean 8184, max ~8600)
#define TILE   2048               // edges per scat1 block
#define EPT    8                  // edges per thread in scat1

using f16x8 = __attribute__((ext_vector_type(8))) _Float16;
using f32x4 = __attribute__((ext_vector_type(4))) float;
using u16x8 = __attribute__((ext_vector_type(8))) unsigned short;

// Pass 1: bin base edges (fwd+inv records) by target-node range.
// NT hints on single-use streams (inputs, gRecs) to keep MALL free for W1.
__global__ __launch_bounds__(256) void scat1_kernel(
        const int* __restrict__ src, const int* __restrict__ rel,
        const int* __restrict__ dst,
        unsigned* __restrict__ gBinCur, unsigned* __restrict__ gRecs) {
    __shared__ unsigned binCnt[NBIN], binOff[NBIN], binBase[NBIN];
    const int tid = threadIdx.x;
    for (int i = tid; i < NBIN; i += 256) { binCnt[i] = 0u; binOff[i] = 0u; }
    __syncthreads();

    const int e0 = blockIdx.x * TILE;
    unsigned rec[2 * EPT], bn[2 * EPT];
    bool val[EPT];
    #pragma unroll
    for (int k = 0; k < EPT; ++k) {
        int e = e0 + k * 256 + tid;
        val[k] = (e < EB);
        unsigned s = 0, r = 0, o = 0;
        if (val[k]) {
            s = (unsigned)__builtin_nontemporal_load(src + e);
            r = (unsigned)__builtin_nontemporal_load(rel + e);
            o = (unsigned)__builtin_nontemporal_load(dst + e);
        }
        bn[2*k]    = s >> 7;
        rec[2*k]   = ((s & 127u) << 22) | (r << 16) | o;
        bn[2*k+1]  = o >> 7;
        rec[2*k+1] = ((o & 127u) << 22) | ((r + NRELB) << 16) | s;
    }
    #pragma unroll
    for (int k = 0; k < EPT; ++k)
        if (val[k]) {
            atomicAdd(&binCnt[bn[2*k]], 1u);
            atomicAdd(&binCnt[bn[2*k+1]], 1u);
        }
    __syncthreads();
    for (int b = tid; b < NBIN; b += 256) {
        unsigned c = binCnt[b];
        if (c) binBase[b] = atomicAdd(&gBinCur[b], c);
    }
    __syncthreads();
    #pragma unroll
    for (int k = 0; k < 2 * EPT; ++k)
        if (val[k >> 1]) {
            unsigned b = bn[k];
            unsigned pos = binBase[b] + atomicAdd(&binOff[b], 1u);
            if (pos < BINCAP)
                __builtin_nontemporal_store(rec[k], &gRecs[(size_t)b * BINCAP + pos]);
        }
}

// Pass 2: one block per bin (128 nodes). Dense bucket writes; zero global atomics.
__global__ __launch_bounds__(256) void scat2_kernel(
        const unsigned* __restrict__ gBinCur, const unsigned* __restrict__ gRecs,
        unsigned* __restrict__ cnt, unsigned* __restrict__ ekey) {
    __shared__ unsigned off[128];
    const int b = blockIdx.x, tid = threadIdx.x;
    if (tid < 128) off[tid] = 1u;        // slot 0 reserved for self-loop
    __syncthreads();
    const unsigned M = min(gBinCur[b], (unsigned)BINCAP);
    const unsigned* recs = gRecs + (size_t)b * BINCAP;
    for (unsigned i0 = 0; i0 < M; i0 += 1024) {
        unsigned i;
        unsigned r0 = 0, r1 = 0, r2 = 0, r3 = 0;
        bool v0, v1, v2, v3;
        i = i0 + tid;        v0 = i < M; if (v0) r0 = __builtin_nontemporal_load(recs + i);
        i = i0 + 256 + tid;  v1 = i < M; if (v1) r1 = __builtin_nontemporal_load(recs + i);
        i = i0 + 512 + tid;  v2 = i < M; if (v2) r2 = __builtin_nontemporal_load(recs + i);
        i = i0 + 768 + tid;  v3 = i < M; if (v3) r3 = __builtin_nontemporal_load(recs + i);
        if (v0) {
            unsigned sl = r0 >> 22, slot = atomicAdd(&off[sl], 1u), n = b * 128u + sl;
            if (slot < STRIDE && n < NN) ekey[(size_t)n * STRIDE + slot] = r0 & 0x3FFFFFu;
        }
        if (v1) {
            unsigned sl = r1 >> 22, slot = atomicAdd(&off[sl], 1u), n = b * 128u + sl;
            if (slot < STRIDE && n < NN) ekey[(size_t)n * STRIDE + slot] = r1 & 0x3FFFFFu;
        }
        if (v2) {
            unsigned sl = r2 >> 22, slot = atomicAdd(&off[sl], 1u), n = b * 128u + sl;
            if (slot < STRIDE && n < NN) ekey[(size_t)n * STRIDE + slot] = r2 & 0x3FFFFFu;
        }
        if (v3) {
            unsigned sl = r3 >> 22, slot = atomicAdd(&off[sl], 1u), n = b * 128u + sl;
            if (slot < STRIDE && n < NN) ekey[(size_t)n * STRIDE + slot] = r3 & 0x3FFFFFu;
        }
    }
    __syncthreads();
    if (tid < 128) {
        unsigned n = b * 128u + (unsigned)tid;
        if (n < NN) {
            ekey[(size_t)n * STRIDE] = ((unsigned)(2 * NRELB) << 16) | n;
            cnt[n] = min(off[tid], (unsigned)STRIDE);
        }
    }
}

// Build the three A-fragments (rows m, m+16, m+32 of the indicator matrix)
// in registers from the chunk's rel values.
__device__ __forceinline__ void mk_afrags(u16x8 rv, int m,
                                          f16x8& a0, f16x8& a1, f16x8& a2) {
    #pragma unroll
    for (int j = 0; j < 8; ++j) {
        a0[j] = (_Float16)(rv[j] == (unsigned short)m);
        a1[j] = (_Float16)(rv[j] == (unsigned short)(m + 16));
        a2[j] = (_Float16)(rv[j] == (unsigned short)(m + 32));
    }
}

// Layer 1 via per-node mini-MFMA: acc[r][h] = M[48][64] @ W1rows[64][16].
__global__ __launch_bounds__(256) void layer1_kernel(
        const unsigned* __restrict__ ekey, const unsigned* __restrict__ cnt,
        const float* __restrict__ W1, const float* __restrict__ b1,
        float* __restrict__ h) {
    __shared__ __align__(16) _Float16 rT[AGW][16 * PM];
    __shared__ __align__(16) unsigned short relc[AGW][64];
    __shared__ float degL[AGW][48];
    const int wave = threadIdx.x >> 6, lane = threadIdx.x & 63;
    const int n = blockIdx.x * AGW + wave;
    const unsigned* ek = ekey + (size_t)n * STRIDE;
    const int deg = cnt[n];
    const int m = lane & 15;

    if (lane < 48) degL[wave][lane] = 0.f;
    {   // zero rT (finite values required: A=0 masks values, not NaNs)
        unsigned* rz = (unsigned*)&rT[wave][0];
        #pragma unroll
        for (int t = 0; t < 9; ++t) rz[lane + t * 64] = 0u;
    }

    f32x4 d0 = {0.f,0.f,0.f,0.f}, d1 = {0.f,0.f,0.f,0.f}, d2 = {0.f,0.f,0.f,0.f};

    for (int c0 = 0; c0 < deg; c0 += 64) {
        const int degc = min(deg - c0, 64);
        {   // stage rel values (63 = no-relation pad) + degree histogram
            int r = 63;
            if (lane < degc) r = (int)(ek[c0 + lane] >> 16);
            relc[wave][lane] = (unsigned short)r;
            if (lane < degc) atomicAdd(&degL[wave][r], 1.f);
        }
        {   // gather W1 rows -> rT (transposed, f16); clamped tails benign
            const int g = lane >> 2, q = (lane & 3) * 4;
            for (int i = 0; i < degc; i += 16) {
                int kl = min(i + g, degc - 1);
                unsigned key = ek[c0 + kl];
                int r = key >> 16, o = key & 0xFFFF;
                float4 v = *(const float4*)(W1 + ((size_t)(r * NN + o)) * NHID + q);
                rT[wave][(q + 0) * PM + kl] = (_Float16)v.x;
                rT[wave][(q + 1) * PM + kl] = (_Float16)v.y;
                rT[wave][(q + 2) * PM + kl] = (_Float16)v.z;
                rT[wave][(q + 3) * PM + kl] = (_Float16)v.w;
            }
        }
        const int nkt = (degc > 32) ? 2 : 1;
        for (int kt = 0; kt < nkt; ++kt) {
            const int ko = kt * 32 + (lane >> 4) * 8;
            f16x8 b = *(const f16x8*)&rT[wave][m * PM + ko];
            u16x8 rv = *(const u16x8*)&relc[wave][ko];
            f16x8 a0, a1, a2;
            mk_afrags(rv, m, a0, a1, a2);
            d0 = __builtin_amdgcn_mfma_f32_16x16x32_f16(a0, b, d0, 0, 0, 0);
            d1 = __builtin_amdgcn_mfma_f32_16x16x32_f16(a1, b, d1, 0, 0, 0);
            d2 = __builtin_amdgcn_mfma_f32_16x16x32_f16(a2, b, d2, 0, 0, 0);
        }
    }

    float partial = 0.f;
    const int rg = lane >> 4;
    #pragma unroll
    for (int mt = 0; mt < 3; ++mt) {
        f32x4 dv = (mt == 0) ? d0 : (mt == 1) ? d1 : d2;
        #pragma unroll
        for (int c = 0; c < 4; ++c) {
            int r = mt * 16 + rg * 4 + c;
            if (r < RR) {
                float dgc = degL[wave][r];
                partial += (dgc != 0.f) ? dv[c] / dgc : 0.f;
            }
        }
    }
    partial += __shfl_xor(partial, 16);
    partial += __shfl_xor(partial, 32);
    if (lane < NHID) h[n * NHID + lane] = fmaxf(partial + b1[lane], 0.f);
}

// Pre-pack W2 -> f16 B-fragments for mfma_f32_16x16x32_f16.
__global__ void pack_kernel(const float* __restrict__ W2, _Float16* __restrict__ W2f) {
    int idx = blockIdx.x * blockDim.x + threadIdx.x;
    if (idx >= NCT * NKB * 64 * 8) return;
    int j = idx & 7, lane = (idx >> 3) & 63, t = idx >> 9;
    int kb = t % NKB, ct = t / NKB;
    int k = kb * 32 + (lane >> 4) * 8 + j;
    int c = ct * 16 + (lane & 15);
    W2f[idx] = (_Float16)((k < RH && c < NCLASS) ? W2[k * NCLASS + c] : 0.f);
}

// FUSED layer-2: 512 threads, 8 waves. Phase 1: each wave aggregates 2 nodes.
// Phase 2: split-K MFMA gemm (2 waves per class-tile). Phase 3: sum partials,
// log-softmax, NT store to out.
__global__ __launch_bounds__(512) void agg_gemm_kernel(
        const unsigned* __restrict__ ekey, const unsigned* __restrict__ cnt,
        const float* __restrict__ h, const _Float16* __restrict__ W2f,
        const float* __restrict__ b2, float* __restrict__ out) {
    __shared__ __align__(16) _Float16 rT[FW][16 * PM];
    __shared__ __align__(16) unsigned short relc[FW][64];
    __shared__ float degL[FW][48];
    __shared__ __align__(16) _Float16 afL[FNPB][APAD];   // scaled af tile (f16)
    __shared__ float lgp[2][FNPB][68];                   // split-K logit partials
    const int wave = threadIdx.x >> 6, lane = threadIdx.x & 63;
    const int nbase = blockIdx.x * FNPB;
    const int m = lane & 15, g = lane >> 4;

    {   // zero rT once (finite values required; stale values masked by A=0)
        unsigned* rz = (unsigned*)&rT[wave][0];
        #pragma unroll
        for (int t = 0; t < 9; ++t) rz[lane + t * 64] = 0u;
    }

    // ---- Phase 1: aggregate 2 nodes per wave ----
    for (int nd = 0; nd < 2; ++nd) {
        const int widx = wave * 2 + nd;
        const int n = nbase + widx;
        const unsigned* ek = ekey + (size_t)n * STRIDE;
        const int deg = (n < NN) ? (int)cnt[n] : 0;

        if (lane < 48) degL[wave][lane] = 0.f;

        f32x4 d0 = {0.f,0.f,0.f,0.f}, d1 = {0.f,0.f,0.f,0.f}, d2 = {0.f,0.f,0.f,0.f};

        for (int c0 = 0; c0 < deg; c0 += 64) {
            const int degc = min(deg - c0, 64);
            {
                int r = 63;
                if (lane < degc) r = (int)(ek[c0 + lane] >> 16);
                relc[wave][lane] = (unsigned short)r;
                if (lane < degc) atomicAdd(&degL[wave][r], 1.f);
            }
            {   // gather h rows -> rT (transposed, f16)
                const int gg = lane >> 2, q = (lane & 3) * 4;
                for (int i = 0; i < degc; i += 16) {
                    int kl = min(i + gg, degc - 1);
                    unsigned key = ek[c0 + kl];
                    float4 v = *(const float4*)(h + (key & 0xFFFF) * NHID + q);
                    rT[wave][(q + 0) * PM + kl] = (_Float16)v.x;
                    rT[wave][(q + 1) * PM + kl] = (_Float16)v.y;
                    rT[wave][(q + 2) * PM + kl] = (_Float16)v.z;
                    rT[wave][(q + 3) * PM + kl] = (_Float16)v.w;
                }
            }
            const int nkt = (degc > 32) ? 2 : 1;
            for (int kt = 0; kt < nkt; ++kt) {
                const int ko = kt * 32 + g * 8;
                f16x8 b = *(const f16x8*)&rT[wave][m * PM + ko];
                u16x8 rv = *(const u16x8*)&relc[wave][ko];
                f16x8 a0, a1, a2;
                mk_afrags(rv, m, a0, a1, a2);
                d0 = __builtin_amdgcn_mfma_f32_16x16x32_f16(a0, b, d0, 0, 0, 0);
                d1 = __builtin_amdgcn_mfma_f32_16x16x32_f16(a1, b, d1, 0, 0, 0);
                d2 = __builtin_amdgcn_mfma_f32_16x16x32_f16(a2, b, d2, 0, 0, 0);
            }
        }

        // scale by 1/deg_r and write af row into LDS (r==41 row = pad zeros)
        const int hh = lane & 15, rg = lane >> 4;
        #pragma unroll
        for (int mt = 0; mt < 3; ++mt) {
            f32x4 dv = (mt == 0) ? d0 : (mt == 1) ? d1 : d2;
            #pragma unroll
            for (int c = 0; c < 4; ++c) {
                int r = mt * 16 + rg * 4 + c;
                if (r <= RR) {
                    float val = 0.f;
                    if (r < RR) {
                        float dgc = degL[wave][r];
                        val = (dgc != 0.f) ? dv[c] / dgc : 0.f;
                    }
                    afL[widx][r * 16 + hh] = (_Float16)val;
                }
            }
        }
    }
    __syncthreads();

    // ---- Phase 2: split-K MFMA gemm; wave = (kh, ct) ----
    {
        const int ct = wave & 3, kh = wave >> 2;
        const int kb0 = kh ? 11 : 0, kb1 = kh ? NKB : 11;
        f32x4 acc = {0.f, 0.f, 0.f, 0.f};
        const _Float16* wrow = W2f + (size_t)lane * 8;
        for (int kb = kb0; kb < kb1; ++kb) {
            f16x8 a = *(const f16x8*)&afL[m][kb * 32 + g * 8];
            f16x8 b = *(const f16x8*)(wrow + (size_t)(ct * NKB + kb) * 512);
            acc = __builtin_amdgcn_mfma_f32_16x16x32_f16(a, b, acc, 0, 0, 0);
        }
        int c = ct * 16 + m;
        #pragma unroll
        for (int reg = 0; reg < 4; ++reg)
            lgp[kh][g * 4 + reg][c] = acc[reg];
    }
    __syncthreads();

    // ---- Phase 3: sum partials + per-row log-softmax; wave handles 2 rows ----
    for (int rr = 0; rr < 2; ++rr) {
        const int row = wave * 2 + rr;
        const int n = nbase + row;
        float x = -INFINITY;
        if (lane < NCLASS)
            x = lgp[0][row][lane] + lgp[1][row][lane] + b2[lane];
        float mx = x;
        #pragma unroll
        for (int off = 32; off; off >>= 1) mx = fmaxf(mx, __shfl_xor(mx, off));
        float ex = (lane < NCLASS) ? expf(x - mx) : 0.f;
        float ss = ex;
        #pragma unroll
        for (int off = 32; off; off >>= 1) ss += __shfl_xor(ss, off);
        float ls = logf(ss) + mx;
        if (lane < NCLASS && n < NN)
            __builtin_nontemporal_store(x - ls, &out[n * NCLASS + lane]);
    }
}

extern "C" void kernel_launch(void* const* d_in, const int* in_sizes, int n_in,
                              void* d_out, int out_size, void* d_ws, size_t ws_size,
                              hipStream_t stream) {
    const int*   src = (const int*)d_in[0];
    const int*   rel = (const int*)d_in[1];
    const int*   dst = (const int*)d_in[2];
    const float* W1  = (const float*)d_in[3];
    const float* b1  = (const float*)d_in[4];
    const float* W2  = (const float*)d_in[5];
    const float* b2  = (const float*)d_in[6];
    float* out = (float*)d_out;

    unsigned* cnt  = (unsigned*)d_ws;                        // NN
    unsigned* ekey = cnt + NN;                               // NN*STRIDE (25.6 MB)
    float*    h    = (float*)(ekey + (size_t)NN * STRIDE);   // NN*NHID (3.2 MB)
    _Float16* W2f  = (_Float16*)(h + (size_t)NN * NHID);     // 86 KB
    unsigned* gBinCur = (unsigned*)(W2f + NCT * NKB * 512);  // 512 u32
    unsigned* gRecs   = gBinCur + 512;                       // NBIN*BINCAP (19.2 MB)

    const int blk = 256;
    hipMemsetAsync(gBinCur, 0, 512 * sizeof(unsigned), stream);
    scat1_kernel<<<(EB + TILE - 1) / TILE, blk, 0, stream>>>(src, rel, dst, gBinCur, gRecs);
    scat2_kernel<<<NBIN, blk, 0, stream>>>(gBinCur, gRecs, cnt, ekey);
    pack_kernel<<<(NCT * NKB * 512 + blk - 1) / blk, blk, 0, stream>>>(W2, W2f);
    layer1_kernel<<<NN / AGW, blk, 0, stream>>>(ekey, cnt, W1, b1, h);
    agg_gemm_kernel<<<NROWS / FNPB, 512, 0, stream>>>(ekey, cnt, h, W2f, b2, out);
}

// Round 19
// 217.097 us; speedup vs baseline: 1.4156x; 1.4156x over previous
//
#include <hip/hip_runtime.h>

#define NN     50000
#define NRELB  20
#define RR     (2*NRELB + 1)      // 41
#define NHID   16
#define NCLASS 50
#define EB     1600000
#define RH     (RR * NHID)        // 656
#define STRIDE 128                // per-node bucket capacity (max deg+1 ~ 105)
#define KPAD   672                // 656 padded to 21*32
#define APAD   680                // afL row stride (elems)
#define NKB    21                 // K-blocks of 32 in the gemm
#define NCT    4                  // class tiles of 16 (64 >= 50)
#define NROWS  50048              // 3128*16 node rows (padded)
#define PM     72                 // padded k-stride (elems) for rT
#define AGW    4                  // waves (= nodes) per block (layer1)
#define FNPB   16                 // nodes per block (fused agg+gemm)
#define FW     8                  // waves per block (fused agg+gemm)

#define NBIN   391                // node-range bins (128 nodes each, s>>7)
#define BINCAP 12288              // records per bin (mean 8184, max ~8600)
#define TILE   2048               // edges per scat1 block
#define EPT    8                  // edges per thread in scat1

using f16x8 = __attribute__((ext_vector_type(8))) _Float16;
using f32x4 = __attribute__((ext_vector_type(4))) float;
using u16x8 = __attribute__((ext_vector_type(8))) unsigned short;

// Pass 1: bin base edges (fwd+inv records) by target-node range.
// PLAIN stores: per-bin appends are contiguous runs that L2 write-combines
// into full lines (NT stores bypass L2 and cost 6x write traffic - R18).
__global__ __launch_bounds__(256) void scat1_kernel(
        const int* __restrict__ src, const int* __restrict__ rel,
        const int* __restrict__ dst,
        unsigned* __restrict__ gBinCur, unsigned* __restrict__ gRecs) {
    __shared__ unsigned binCnt[NBIN], binOff[NBIN], binBase[NBIN];
    const int tid = threadIdx.x;
    for (int i = tid; i < NBIN; i += 256) { binCnt[i] = 0u; binOff[i] = 0u; }
    __syncthreads();

    const int e0 = blockIdx.x * TILE;
    unsigned rec[2 * EPT], bn[2 * EPT];
    bool val[EPT];
    #pragma unroll
    for (int k = 0; k < EPT; ++k) {
        int e = e0 + k * 256 + tid;
        val[k] = (e < EB);
        unsigned s = 0, r = 0, o = 0;
        if (val[k]) { s = (unsigned)src[e]; r = (unsigned)rel[e]; o = (unsigned)dst[e]; }
        bn[2*k]    = s >> 7;
        rec[2*k]   = ((s & 127u) << 22) | (r << 16) | o;
        bn[2*k+1]  = o >> 7;
        rec[2*k+1] = ((o & 127u) << 22) | ((r + NRELB) << 16) | s;
    }
    #pragma unroll
    for (int k = 0; k < EPT; ++k)
        if (val[k]) {
            atomicAdd(&binCnt[bn[2*k]], 1u);
            atomicAdd(&binCnt[bn[2*k+1]], 1u);
        }
    __syncthreads();
    for (int b = tid; b < NBIN; b += 256) {
        unsigned c = binCnt[b];
        if (c) binBase[b] = atomicAdd(&gBinCur[b], c);
    }
    __syncthreads();
    #pragma unroll
    for (int k = 0; k < 2 * EPT; ++k)
        if (val[k >> 1]) {
            unsigned b = bn[k];
            unsigned pos = binBase[b] + atomicAdd(&binOff[b], 1u);
            if (pos < BINCAP) gRecs[(size_t)b * BINCAP + pos] = rec[k];
        }
}

// Pass 2: one block per bin (128 nodes). Dense bucket writes; zero global atomics.
__global__ __launch_bounds__(256) void scat2_kernel(
        const unsigned* __restrict__ gBinCur, const unsigned* __restrict__ gRecs,
        unsigned* __restrict__ cnt, unsigned* __restrict__ ekey) {
    __shared__ unsigned off[128];
    const int b = blockIdx.x, tid = threadIdx.x;
    if (tid < 128) off[tid] = 1u;        // slot 0 reserved for self-loop
    __syncthreads();
    const unsigned M = min(gBinCur[b], (unsigned)BINCAP);
    const unsigned* recs = gRecs + (size_t)b * BINCAP;
    for (unsigned i0 = 0; i0 < M; i0 += 1024) {
        unsigned i;
        unsigned r0 = 0, r1 = 0, r2 = 0, r3 = 0;
        bool v0, v1, v2, v3;
        i = i0 + tid;        v0 = i < M; if (v0) r0 = recs[i];
        i = i0 + 256 + tid;  v1 = i < M; if (v1) r1 = recs[i];
        i = i0 + 512 + tid;  v2 = i < M; if (v2) r2 = recs[i];
        i = i0 + 768 + tid;  v3 = i < M; if (v3) r3 = recs[i];
        if (v0) {
            unsigned sl = r0 >> 22, slot = atomicAdd(&off[sl], 1u), n = b * 128u + sl;
            if (slot < STRIDE && n < NN) ekey[(size_t)n * STRIDE + slot] = r0 & 0x3FFFFFu;
        }
        if (v1) {
            unsigned sl = r1 >> 22, slot = atomicAdd(&off[sl], 1u), n = b * 128u + sl;
            if (slot < STRIDE && n < NN) ekey[(size_t)n * STRIDE + slot] = r1 & 0x3FFFFFu;
        }
        if (v2) {
            unsigned sl = r2 >> 22, slot = atomicAdd(&off[sl], 1u), n = b * 128u + sl;
            if (slot < STRIDE && n < NN) ekey[(size_t)n * STRIDE + slot] = r2 & 0x3FFFFFu;
        }
        if (v3) {
            unsigned sl = r3 >> 22, slot = atomicAdd(&off[sl], 1u), n = b * 128u + sl;
            if (slot < STRIDE && n < NN) ekey[(size_t)n * STRIDE + slot] = r3 & 0x3FFFFFu;
        }
    }
    __syncthreads();
    if (tid < 128) {
        unsigned n = b * 128u + (unsigned)tid;
        if (n < NN) {
            ekey[(size_t)n * STRIDE] = ((unsigned)(2 * NRELB) << 16) | n;
            cnt[n] = min(off[tid], (unsigned)STRIDE);
        }
    }
}

// Build the three A-fragments (rows m, m+16, m+32 of the indicator matrix)
// in registers from the chunk's rel values.
__device__ __forceinline__ void mk_afrags(u16x8 rv, int m,
                                          f16x8& a0, f16x8& a1, f16x8& a2) {
    #pragma unroll
    for (int j = 0; j < 8; ++j) {
        a0[j] = (_Float16)(rv[j] == (unsigned short)m);
        a1[j] = (_Float16)(rv[j] == (unsigned short)(m + 16));
        a2[j] = (_Float16)(rv[j] == (unsigned short)(m + 32));
    }
}

// Layer 1 via per-node mini-MFMA: acc[r][h] = M[48][64] @ W1rows[64][16].
__global__ __launch_bounds__(256) void layer1_kernel(
        const unsigned* __restrict__ ekey, const unsigned* __restrict__ cnt,
        const float* __restrict__ W1, const float* __restrict__ b1,
        float* __restrict__ h) {
    __shared__ __align__(16) _Float16 rT[AGW][16 * PM];
    __shared__ __align__(16) unsigned short relc[AGW][64];
    __shared__ float degL[AGW][48];
    const int wave = threadIdx.x >> 6, lane = threadIdx.x & 63;
    const int n = blockIdx.x * AGW + wave;
    const unsigned* ek = ekey + (size_t)n * STRIDE;
    const int deg = cnt[n];
    const int m = lane & 15;

    if (lane < 48) degL[wave][lane] = 0.f;
    {   // zero rT (finite values required: A=0 masks values, not NaNs)
        unsigned* rz = (unsigned*)&rT[wave][0];
        #pragma unroll
        for (int t = 0; t < 9; ++t) rz[lane + t * 64] = 0u;
    }

    f32x4 d0 = {0.f,0.f,0.f,0.f}, d1 = {0.f,0.f,0.f,0.f}, d2 = {0.f,0.f,0.f,0.f};

    for (int c0 = 0; c0 < deg; c0 += 64) {
        const int degc = min(deg - c0, 64);
        {   // stage rel values (63 = no-relation pad) + degree histogram
            int r = 63;
            if (lane < degc) r = (int)(ek[c0 + lane] >> 16);
            relc[wave][lane] = (unsigned short)r;
            if (lane < degc) atomicAdd(&degL[wave][r], 1.f);
        }
        {   // gather W1 rows -> rT (transposed, f16); clamped tails benign
            const int g = lane >> 2, q = (lane & 3) * 4;
            for (int i = 0; i < degc; i += 16) {
                int kl = min(i + g, degc - 1);
                unsigned key = ek[c0 + kl];
                int r = key >> 16, o = key & 0xFFFF;
                float4 v = *(const float4*)(W1 + ((size_t)(r * NN + o)) * NHID + q);
                rT[wave][(q + 0) * PM + kl] = (_Float16)v.x;
                rT[wave][(q + 1) * PM + kl] = (_Float16)v.y;
                rT[wave][(q + 2) * PM + kl] = (_Float16)v.z;
                rT[wave][(q + 3) * PM + kl] = (_Float16)v.w;
            }
        }
        const int nkt = (degc > 32) ? 2 : 1;
        for (int kt = 0; kt < nkt; ++kt) {
            const int ko = kt * 32 + (lane >> 4) * 8;
            f16x8 b = *(const f16x8*)&rT[wave][m * PM + ko];
            u16x8 rv = *(const u16x8*)&relc[wave][ko];
            f16x8 a0, a1, a2;
            mk_afrags(rv, m, a0, a1, a2);
            d0 = __builtin_amdgcn_mfma_f32_16x16x32_f16(a0, b, d0, 0, 0, 0);
            d1 = __builtin_amdgcn_mfma_f32_16x16x32_f16(a1, b, d1, 0, 0, 0);
            d2 = __builtin_amdgcn_mfma_f32_16x16x32_f16(a2, b, d2, 0, 0, 0);
        }
    }

    float partial = 0.f;
    const int rg = lane >> 4;
    #pragma unroll
    for (int mt = 0; mt < 3; ++mt) {
        f32x4 dv = (mt == 0) ? d0 : (mt == 1) ? d1 : d2;
        #pragma unroll
        for (int c = 0; c < 4; ++c) {
            int r = mt * 16 + rg * 4 + c;
            if (r < RR) {
                float dgc = degL[wave][r];
                partial += (dgc != 0.f) ? dv[c] / dgc : 0.f;
            }
        }
    }
    partial += __shfl_xor(partial, 16);
    partial += __shfl_xor(partial, 32);
    if (lane < NHID) h[n * NHID + lane] = fmaxf(partial + b1[lane], 0.f);
}

// Pre-pack W2 -> f16 B-fragments for mfma_f32_16x16x32_f16.
__global__ void pack_kernel(const float* __restrict__ W2, _Float16* __restrict__ W2f) {
    int idx = blockIdx.x * blockDim.x + threadIdx.x;
    if (idx >= NCT * NKB * 64 * 8) return;
    int j = idx & 7, lane = (idx >> 3) & 63, t = idx >> 9;
    int kb = t % NKB, ct = t / NKB;
    int k = kb * 32 + (lane >> 4) * 8 + j;
    int c = ct * 16 + (lane & 15);
    W2f[idx] = (_Float16)((k < RH && c < NCLASS) ? W2[k * NCLASS + c] : 0.f);
}

// FUSED layer-2: 512 threads, 8 waves. Phase 1: each wave aggregates 2 nodes.
// Phase 2: split-K MFMA gemm (2 waves per class-tile). Phase 3: sum partials,
// log-softmax, store to out.
__global__ __launch_bounds__(512) void agg_gemm_kernel(
        const unsigned* __restrict__ ekey, const unsigned* __restrict__ cnt,
        const float* __restrict__ h, const _Float16* __restrict__ W2f,
        const float* __restrict__ b2, float* __restrict__ out) {
    __shared__ __align__(16) _Float16 rT[FW][16 * PM];
    __shared__ __align__(16) unsigned short relc[FW][64];
    __shared__ float degL[FW][48];
    __shared__ __align__(16) _Float16 afL[FNPB][APAD];   // scaled af tile (f16)
    __shared__ float lgp[2][FNPB][68];                   // split-K logit partials
    const int wave = threadIdx.x >> 6, lane = threadIdx.x & 63;
    const int nbase = blockIdx.x * FNPB;
    const int m = lane & 15, g = lane >> 4;

    {   // zero rT once (finite values required; stale values masked by A=0)
        unsigned* rz = (unsigned*)&rT[wave][0];
        #pragma unroll
        for (int t = 0; t < 9; ++t) rz[lane + t * 64] = 0u;
    }

    // ---- Phase 1: aggregate 2 nodes per wave ----
    for (int nd = 0; nd < 2; ++nd) {
        const int widx = wave * 2 + nd;
        const int n = nbase + widx;
        const unsigned* ek = ekey + (size_t)n * STRIDE;
        const int deg = (n < NN) ? (int)cnt[n] : 0;

        if (lane < 48) degL[wave][lane] = 0.f;

        f32x4 d0 = {0.f,0.f,0.f,0.f}, d1 = {0.f,0.f,0.f,0.f}, d2 = {0.f,0.f,0.f,0.f};

        for (int c0 = 0; c0 < deg; c0 += 64) {
            const int degc = min(deg - c0, 64);
            {
                int r = 63;
                if (lane < degc) r = (int)(ek[c0 + lane] >> 16);
                relc[wave][lane] = (unsigned short)r;
                if (lane < degc) atomicAdd(&degL[wave][r], 1.f);
            }
            {   // gather h rows -> rT (transposed, f16)
                const int gg = lane >> 2, q = (lane & 3) * 4;
                for (int i = 0; i < degc; i += 16) {
                    int kl = min(i + gg, degc - 1);
                    unsigned key = ek[c0 + kl];
                    float4 v = *(const float4*)(h + (key & 0xFFFF) * NHID + q);
                    rT[wave][(q + 0) * PM + kl] = (_Float16)v.x;
                    rT[wave][(q + 1) * PM + kl] = (_Float16)v.y;
                    rT[wave][(q + 2) * PM + kl] = (_Float16)v.z;
                    rT[wave][(q + 3) * PM + kl] = (_Float16)v.w;
                }
            }
            const int nkt = (degc > 32) ? 2 : 1;
            for (int kt = 0; kt < nkt; ++kt) {
                const int ko = kt * 32 + g * 8;
                f16x8 b = *(const f16x8*)&rT[wave][m * PM + ko];
                u16x8 rv = *(const u16x8*)&relc[wave][ko];
                f16x8 a0, a1, a2;
                mk_afrags(rv, m, a0, a1, a2);
                d0 = __builtin_amdgcn_mfma_f32_16x16x32_f16(a0, b, d0, 0, 0, 0);
                d1 = __builtin_amdgcn_mfma_f32_16x16x32_f16(a1, b, d1, 0, 0, 0);
                d2 = __builtin_amdgcn_mfma_f32_16x16x32_f16(a2, b, d2, 0, 0, 0);
            }
        }

        // scale by 1/deg_r and write af row into LDS (r==41 row = pad zeros)
        const int hh = lane & 15, rg = lane >> 4;
        #pragma unroll
        for (int mt = 0; mt < 3; ++mt) {
            f32x4 dv = (mt == 0) ? d0 : (mt == 1) ? d1 : d2;
            #pragma unroll
            for (int c = 0; c < 4; ++c) {
                int r = mt * 16 + rg * 4 + c;
                if (r <= RR) {
                    float val = 0.f;
                    if (r < RR) {
                        float dgc = degL[wave][r];
                        val = (dgc != 0.f) ? dv[c] / dgc : 0.f;
                    }
                    afL[widx][r * 16 + hh] = (_Float16)val;
                }
            }
        }
    }
    __syncthreads();

    // ---- Phase 2: split-K MFMA gemm; wave = (kh, ct) ----
    {
        const int ct = wave & 3, kh = wave >> 2;
        const int kb0 = kh ? 11 : 0, kb1 = kh ? NKB : 11;
        f32x4 acc = {0.f, 0.f, 0.f, 0.f};
        const _Float16* wrow = W2f + (size_t)lane * 8;
        for (int kb = kb0; kb < kb1; ++kb) {
            f16x8 a = *(const f16x8*)&afL[m][kb * 32 + g * 8];
            f16x8 b = *(const f16x8*)(wrow + (size_t)(ct * NKB + kb) * 512);
            acc = __builtin_amdgcn_mfma_f32_16x16x32_f16(a, b, acc, 0, 0, 0);
        }
        int c = ct * 16 + m;
        #pragma unroll
        for (int reg = 0; reg < 4; ++reg)
            lgp[kh][g * 4 + reg][c] = acc[reg];
    }
    __syncthreads();

    // ---- Phase 3: sum partials + per-row log-softmax; wave handles 2 rows ----
    for (int rr = 0; rr < 2; ++rr) {
        const int row = wave * 2 + rr;
        const int n = nbase + row;
        float x = -INFINITY;
        if (lane < NCLASS)
            x = lgp[0][row][lane] + lgp[1][row][lane] + b2[lane];
        float mx = x;
        #pragma unroll
        for (int off = 32; off; off >>= 1) mx = fmaxf(mx, __shfl_xor(mx, off));
        float ex = (lane < NCLASS) ? expf(x - mx) : 0.f;
        float ss = ex;
        #pragma unroll
        for (int off = 32; off; off >>= 1) ss += __shfl_xor(ss, off);
        float ls = logf(ss) + mx;
        if (lane < NCLASS && n < NN)
            __builtin_nontemporal_store(x - ls, &out[n * NCLASS + lane]);
    }
}

extern "C" void kernel_launch(void* const* d_in, const int* in_sizes, int n_in,
                              void* d_out, int out_size, void* d_ws, size_t ws_size,
                              hipStream_t stream) {
    const int*   src = (const int*)d_in[0];
    const int*   rel = (const int*)d_in[1];
    const int*   dst = (const int*)d_in[2];
    const float* W1  = (const float*)d_in[3];
    const float* b1  = (const float*)d_in[4];
    const float* W2  = (const float*)d_in[5];
    const float* b2  = (const float*)d_in[6];
    float* out = (float*)d_out;

    unsigned* cnt  = (unsigned*)d_ws;                        // NN
    unsigned* ekey = cnt + NN;                               // NN*STRIDE (25.6 MB)
    float*    h    = (float*)(ekey + (size_t)NN * STRIDE);   // NN*NHID (3.2 MB)
    _Float16* W2f  = (_Float16*)(h + (size_t)NN * NHID);     // 86 KB
    unsigned* gBinCur = (unsigned*)(W2f + NCT * NKB * 512);  // 512 u32
    unsigned* gRecs   = gBinCur + 512;                       // NBIN*BINCAP (19.2 MB)

    const int blk = 256;
    hipMemsetAsync(gBinCur, 0, 512 * sizeof(unsigned), stream);
    scat1_kernel<<<(EB + TILE - 1) / TILE, blk, 0, stream>>>(src, rel, dst, gBinCur, gRecs);
    scat2_kernel<<<NBIN, blk, 0, stream>>>(gBinCur, gRecs, cnt, ekey);
    pack_kernel<<<(NCT * NKB * 512 + blk - 1) / blk, blk, 0, stream>>>(W2, W2f);
    layer1_kernel<<<NN / AGW, blk, 0, stream>>>(ekey, cnt, W1, b1, h);
    agg_gemm_kernel<<<NROWS / FNPB, 512, 0, stream>>>(ekey, cnt, h, W2f, b2, out);
}

// Round 20
// 207.822 us; speedup vs baseline: 1.4788x; 1.0446x over previous
//
#include <hip/hip_runtime.h>

#define NN     50000
#define NRELB  20
#define RR     (2*NRELB + 1)      // 41
#define NHID   16
#define NCLASS 50
#define EB     1600000
#define RH     (RR * NHID)        // 656
#define STRIDE 128                // per-node bucket capacity (max deg+1 ~ 105)
#define KPAD   672                // 656 padded to 21*32
#define APAD   680                // afL row stride (elems)
#define NKB    21                 // K-blocks of 32 in the gemm
#define NCT    4                  // class tiles of 16 (64 >= 50)
#define NROWS  50048              // 3128*16 node rows (padded)
#define PM     72                 // padded k-stride (elems) for rT
#define AGW    4                  // waves (= nodes) per block (layer1)
#define FNPB   16                 // nodes per block (fused agg+gemm)
#define FW     8                  // waves per block (fused agg+gemm)

#define NBIN   391                // node-range bins (128 nodes each, s>>7)
#define BINCAP 12288              // records per bin (mean 8184, max ~8600)
#define TILE   2048               // edges per scat1 block
#define EPT    8                  // edges per thread in scat1

using f16x8 = __attribute__((ext_vector_type(8))) _Float16;
using f32x4 = __attribute__((ext_vector_type(4))) float;
using u16x8 = __attribute__((ext_vector_type(8))) unsigned short;

// Pass 1: bin base edges (fwd+inv records) by target-node range.
// PLAIN stores: per-bin appends are contiguous runs that L2 write-combines
// into full lines (NT stores bypass L2 and cost 6x write traffic - R18).
__global__ __launch_bounds__(256) void scat1_kernel(
        const int* __restrict__ src, const int* __restrict__ rel,
        const int* __restrict__ dst,
        unsigned* __restrict__ gBinCur, unsigned* __restrict__ gRecs) {
    __shared__ unsigned binCnt[NBIN], binOff[NBIN], binBase[NBIN];
    const int tid = threadIdx.x;
    for (int i = tid; i < NBIN; i += 256) { binCnt[i] = 0u; binOff[i] = 0u; }
    __syncthreads();

    const int e0 = blockIdx.x * TILE;
    unsigned rec[2 * EPT], bn[2 * EPT];
    bool val[EPT];
    #pragma unroll
    for (int k = 0; k < EPT; ++k) {
        int e = e0 + k * 256 + tid;
        val[k] = (e < EB);
        unsigned s = 0, r = 0, o = 0;
        if (val[k]) { s = (unsigned)src[e]; r = (unsigned)rel[e]; o = (unsigned)dst[e]; }
        bn[2*k]    = s >> 7;
        rec[2*k]   = ((s & 127u) << 22) | (r << 16) | o;
        bn[2*k+1]  = o >> 7;
        rec[2*k+1] = ((o & 127u) << 22) | ((r + NRELB) << 16) | s;
    }
    #pragma unroll
    for (int k = 0; k < EPT; ++k)
        if (val[k]) {
            atomicAdd(&binCnt[bn[2*k]], 1u);
            atomicAdd(&binCnt[bn[2*k+1]], 1u);
        }
    __syncthreads();
    for (int b = tid; b < NBIN; b += 256) {
        unsigned c = binCnt[b];
        if (c) binBase[b] = atomicAdd(&gBinCur[b], c);
    }
    __syncthreads();
    #pragma unroll
    for (int k = 0; k < 2 * EPT; ++k)
        if (val[k >> 1]) {
            unsigned b = bn[k];
            unsigned pos = binBase[b] + atomicAdd(&binOff[b], 1u);
            if (pos < BINCAP) gRecs[(size_t)b * BINCAP + pos] = rec[k];
        }
}

// Pass 2: one block per bin (128 nodes). Dense bucket writes; zero global atomics.
__global__ __launch_bounds__(256) void scat2_kernel(
        const unsigned* __restrict__ gBinCur, const unsigned* __restrict__ gRecs,
        unsigned* __restrict__ cnt, unsigned* __restrict__ ekey) {
    __shared__ unsigned off[128];
    const int b = blockIdx.x, tid = threadIdx.x;
    if (tid < 128) off[tid] = 1u;        // slot 0 reserved for self-loop
    __syncthreads();
    const unsigned M = min(gBinCur[b], (unsigned)BINCAP);
    const unsigned* recs = gRecs + (size_t)b * BINCAP;
    for (unsigned i0 = 0; i0 < M; i0 += 1024) {
        unsigned i;
        unsigned r0 = 0, r1 = 0, r2 = 0, r3 = 0;
        bool v0, v1, v2, v3;
        i = i0 + tid;        v0 = i < M; if (v0) r0 = recs[i];
        i = i0 + 256 + tid;  v1 = i < M; if (v1) r1 = recs[i];
        i = i0 + 512 + tid;  v2 = i < M; if (v2) r2 = recs[i];
        i = i0 + 768 + tid;  v3 = i < M; if (v3) r3 = recs[i];
        if (v0) {
            unsigned sl = r0 >> 22, slot = atomicAdd(&off[sl], 1u), n = b * 128u + sl;
            if (slot < STRIDE && n < NN) ekey[(size_t)n * STRIDE + slot] = r0 & 0x3FFFFFu;
        }
        if (v1) {
            unsigned sl = r1 >> 22, slot = atomicAdd(&off[sl], 1u), n = b * 128u + sl;
            if (slot < STRIDE && n < NN) ekey[(size_t)n * STRIDE + slot] = r1 & 0x3FFFFFu;
        }
        if (v2) {
            unsigned sl = r2 >> 22, slot = atomicAdd(&off[sl], 1u), n = b * 128u + sl;
            if (slot < STRIDE && n < NN) ekey[(size_t)n * STRIDE + slot] = r2 & 0x3FFFFFu;
        }
        if (v3) {
            unsigned sl = r3 >> 22, slot = atomicAdd(&off[sl], 1u), n = b * 128u + sl;
            if (slot < STRIDE && n < NN) ekey[(size_t)n * STRIDE + slot] = r3 & 0x3FFFFFu;
        }
    }
    __syncthreads();
    if (tid < 128) {
        unsigned n = b * 128u + (unsigned)tid;
        if (n < NN) {
            ekey[(size_t)n * STRIDE] = ((unsigned)(2 * NRELB) << 16) | n;
            cnt[n] = min(off[tid], (unsigned)STRIDE);
        }
    }
}

// Build the three A-fragments (rows m, m+16, m+32 of the indicator matrix)
// in registers from the chunk's rel values.
__device__ __forceinline__ void mk_afrags(u16x8 rv, int m,
                                          f16x8& a0, f16x8& a1, f16x8& a2) {
    #pragma unroll
    for (int j = 0; j < 8; ++j) {
        a0[j] = (_Float16)(rv[j] == (unsigned short)m);
        a1[j] = (_Float16)(rv[j] == (unsigned short)(m + 16));
        a2[j] = (_Float16)(rv[j] == (unsigned short)(m + 32));
    }
}

// Layer 1 via per-node mini-MFMA: acc[r][h] = M[48][64] @ W1rows[64][16].
// Output h stored as f16 (consumer rounds to f16 anyway; halves gather width
// downstream). W1 gather stays f32: FETCH is line-count-bound (R15/R16).
__global__ __launch_bounds__(256) void layer1_kernel(
        const unsigned* __restrict__ ekey, const unsigned* __restrict__ cnt,
        const float* __restrict__ W1, const float* __restrict__ b1,
        _Float16* __restrict__ h) {
    __shared__ __align__(16) _Float16 rT[AGW][16 * PM];
    __shared__ __align__(16) unsigned short relc[AGW][64];
    __shared__ float degL[AGW][48];
    const int wave = threadIdx.x >> 6, lane = threadIdx.x & 63;
    const int n = blockIdx.x * AGW + wave;
    const unsigned* ek = ekey + (size_t)n * STRIDE;
    const int deg = cnt[n];
    const int m = lane & 15;

    if (lane < 48) degL[wave][lane] = 0.f;
    {   // zero rT (finite values required: A=0 masks values, not NaNs)
        unsigned* rz = (unsigned*)&rT[wave][0];
        #pragma unroll
        for (int t = 0; t < 9; ++t) rz[lane + t * 64] = 0u;
    }

    f32x4 d0 = {0.f,0.f,0.f,0.f}, d1 = {0.f,0.f,0.f,0.f}, d2 = {0.f,0.f,0.f,0.f};

    for (int c0 = 0; c0 < deg; c0 += 64) {
        const int degc = min(deg - c0, 64);
        {   // stage rel values (63 = no-relation pad) + degree histogram
            int r = 63;
            if (lane < degc) r = (int)(ek[c0 + lane] >> 16);
            relc[wave][lane] = (unsigned short)r;
            if (lane < degc) atomicAdd(&degL[wave][r], 1.f);
        }
        {   // gather W1 rows -> rT (transposed, f16); clamped tails benign
            const int g = lane >> 2, q = (lane & 3) * 4;
            for (int i = 0; i < degc; i += 16) {
                int kl = min(i + g, degc - 1);
                unsigned key = ek[c0 + kl];
                int r = key >> 16, o = key & 0xFFFF;
                float4 v = *(const float4*)(W1 + ((size_t)(r * NN + o)) * NHID + q);
                rT[wave][(q + 0) * PM + kl] = (_Float16)v.x;
                rT[wave][(q + 1) * PM + kl] = (_Float16)v.y;
                rT[wave][(q + 2) * PM + kl] = (_Float16)v.z;
                rT[wave][(q + 3) * PM + kl] = (_Float16)v.w;
            }
        }
        const int nkt = (degc > 32) ? 2 : 1;
        for (int kt = 0; kt < nkt; ++kt) {
            const int ko = kt * 32 + (lane >> 4) * 8;
            f16x8 b = *(const f16x8*)&rT[wave][m * PM + ko];
            u16x8 rv = *(const u16x8*)&relc[wave][ko];
            f16x8 a0, a1, a2;
            mk_afrags(rv, m, a0, a1, a2);
            d0 = __builtin_amdgcn_mfma_f32_16x16x32_f16(a0, b, d0, 0, 0, 0);
            d1 = __builtin_amdgcn_mfma_f32_16x16x32_f16(a1, b, d1, 0, 0, 0);
            d2 = __builtin_amdgcn_mfma_f32_16x16x32_f16(a2, b, d2, 0, 0, 0);
        }
    }

    float partial = 0.f;
    const int rg = lane >> 4;
    #pragma unroll
    for (int mt = 0; mt < 3; ++mt) {
        f32x4 dv = (mt == 0) ? d0 : (mt == 1) ? d1 : d2;
        #pragma unroll
        for (int c = 0; c < 4; ++c) {
            int r = mt * 16 + rg * 4 + c;
            if (r < RR) {
                float dgc = degL[wave][r];
                partial += (dgc != 0.f) ? dv[c] / dgc : 0.f;
            }
        }
    }
    partial += __shfl_xor(partial, 16);
    partial += __shfl_xor(partial, 32);
    if (lane < NHID) h[n * NHID + lane] = (_Float16)fmaxf(partial + b1[lane], 0.f);
}

// Pre-pack W2 -> f16 B-fragments for mfma_f32_16x16x32_f16.
__global__ void pack_kernel(const float* __restrict__ W2, _Float16* __restrict__ W2f) {
    int idx = blockIdx.x * blockDim.x + threadIdx.x;
    if (idx >= NCT * NKB * 64 * 8) return;
    int j = idx & 7, lane = (idx >> 3) & 63, t = idx >> 9;
    int kb = t % NKB, ct = t / NKB;
    int k = kb * 32 + (lane >> 4) * 8 + j;
    int c = ct * 16 + (lane & 15);
    W2f[idx] = (_Float16)((k < RH && c < NCLASS) ? W2[k * NCLASS + c] : 0.f);
}

// FUSED layer-2: 512 threads, 8 waves. Phase 1: each wave aggregates 2 nodes
// (f16 h gather, 2 lanes/edge). Phase 2: split-K MFMA gemm. Phase 3: sum
// partials, log-softmax, store.
__global__ __launch_bounds__(512) void agg_gemm_kernel(
        const unsigned* __restrict__ ekey, const unsigned* __restrict__ cnt,
        const _Float16* __restrict__ h, const _Float16* __restrict__ W2f,
        const float* __restrict__ b2, float* __restrict__ out) {
    __shared__ __align__(16) _Float16 rT[FW][16 * PM];
    __shared__ __align__(16) unsigned short relc[FW][64];
    __shared__ float degL[FW][48];
    __shared__ __align__(16) _Float16 afL[FNPB][APAD];   // scaled af tile (f16)
    __shared__ float lgp[2][FNPB][68];                   // split-K logit partials
    const int wave = threadIdx.x >> 6, lane = threadIdx.x & 63;
    const int nbase = blockIdx.x * FNPB;
    const int m = lane & 15, g = lane >> 4;

    {   // zero rT once (finite values required; stale values masked by A=0)
        unsigned* rz = (unsigned*)&rT[wave][0];
        #pragma unroll
        for (int t = 0; t < 9; ++t) rz[lane + t * 64] = 0u;
    }

    // ---- Phase 1: aggregate 2 nodes per wave ----
    for (int nd = 0; nd < 2; ++nd) {
        const int widx = wave * 2 + nd;
        const int n = nbase + widx;
        const unsigned* ek = ekey + (size_t)n * STRIDE;
        const int deg = (n < NN) ? (int)cnt[n] : 0;

        if (lane < 48) degL[wave][lane] = 0.f;

        f32x4 d0 = {0.f,0.f,0.f,0.f}, d1 = {0.f,0.f,0.f,0.f}, d2 = {0.f,0.f,0.f,0.f};

        for (int c0 = 0; c0 < deg; c0 += 64) {
            const int degc = min(deg - c0, 64);
            {
                int r = 63;
                if (lane < degc) r = (int)(ek[c0 + lane] >> 16);
                relc[wave][lane] = (unsigned short)r;
                if (lane < degc) atomicAdd(&degL[wave][r], 1.f);
            }
            {   // gather f16 h rows -> rT; 2 lanes/edge, f16x8 halves
                const int gg = lane >> 1, q = (lane & 1) * 8;
                for (int i = 0; i < degc; i += 32) {
                    int kl = min(i + gg, degc - 1);
                    unsigned key = ek[c0 + kl];
                    f16x8 v = *(const f16x8*)(h + (size_t)(key & 0xFFFF) * NHID + q);
                    #pragma unroll
                    for (int j = 0; j < 8; ++j)
                        rT[wave][(q + j) * PM + kl] = v[j];
                }
            }
            const int nkt = (degc > 32) ? 2 : 1;
            for (int kt = 0; kt < nkt; ++kt) {
                const int ko = kt * 32 + g * 8;
                f16x8 b = *(const f16x8*)&rT[wave][m * PM + ko];
                u16x8 rv = *(const u16x8*)&relc[wave][ko];
                f16x8 a0, a1, a2;
                mk_afrags(rv, m, a0, a1, a2);
                d0 = __builtin_amdgcn_mfma_f32_16x16x32_f16(a0, b, d0, 0, 0, 0);
                d1 = __builtin_amdgcn_mfma_f32_16x16x32_f16(a1, b, d1, 0, 0, 0);
                d2 = __builtin_amdgcn_mfma_f32_16x16x32_f16(a2, b, d2, 0, 0, 0);
            }
        }

        // scale by 1/deg_r and write af row into LDS (r==41 row = pad zeros)
        const int hh = lane & 15, rg = lane >> 4;
        #pragma unroll
        for (int mt = 0; mt < 3; ++mt) {
            f32x4 dv = (mt == 0) ? d0 : (mt == 1) ? d1 : d2;
            #pragma unroll
            for (int c = 0; c < 4; ++c) {
                int r = mt * 16 + rg * 4 + c;
                if (r <= RR) {
                    float val = 0.f;
                    if (r < RR) {
                        float dgc = degL[wave][r];
                        val = (dgc != 0.f) ? dv[c] / dgc : 0.f;
                    }
                    afL[widx][r * 16 + hh] = (_Float16)val;
                }
            }
        }
    }
    __syncthreads();

    // ---- Phase 2: split-K MFMA gemm; wave = (kh, ct) ----
    {
        const int ct = wave & 3, kh = wave >> 2;
        const int kb0 = kh ? 11 : 0, kb1 = kh ? NKB : 11;
        f32x4 acc = {0.f, 0.f, 0.f, 0.f};
        const _Float16* wrow = W2f + (size_t)lane * 8;
        for (int kb = kb0; kb < kb1; ++kb) {
            f16x8 a = *(const f16x8*)&afL[m][kb * 32 + g * 8];
            f16x8 b = *(const f16x8*)(wrow + (size_t)(ct * NKB + kb) * 512);
            acc = __builtin_amdgcn_mfma_f32_16x16x32_f16(a, b, acc, 0, 0, 0);
        }
        int c = ct * 16 + m;
        #pragma unroll
        for (int reg = 0; reg < 4; ++reg)
            lgp[kh][g * 4 + reg][c] = acc[reg];
    }
    __syncthreads();

    // ---- Phase 3: sum partials + per-row log-softmax; wave handles 2 rows ----
    for (int rr = 0; rr < 2; ++rr) {
        const int row = wave * 2 + rr;
        const int n = nbase + row;
        float x = -INFINITY;
        if (lane < NCLASS)
            x = lgp[0][row][lane] + lgp[1][row][lane] + b2[lane];
        float mx = x;
        #pragma unroll
        for (int off = 32; off; off >>= 1) mx = fmaxf(mx, __shfl_xor(mx, off));
        float ex = (lane < NCLASS) ? expf(x - mx) : 0.f;
        float ss = ex;
        #pragma unroll
        for (int off = 32; off; off >>= 1) ss += __shfl_xor(ss, off);
        float ls = logf(ss) + mx;
        if (lane < NCLASS && n < NN)
            __builtin_nontemporal_store(x - ls, &out[n * NCLASS + lane]);
    }
}

extern "C" void kernel_launch(void* const* d_in, const int* in_sizes, int n_in,
                              void* d_out, int out_size, void* d_ws, size_t ws_size,
                              hipStream_t stream) {
    const int*   src = (const int*)d_in[0];
    const int*   rel = (const int*)d_in[1];
    const int*   dst = (const int*)d_in[2];
    const float* W1  = (const float*)d_in[3];
    const float* b1  = (const float*)d_in[4];
    const float* W2  = (const float*)d_in[5];
    const float* b2  = (const float*)d_in[6];
    float* out = (float*)d_out;

    unsigned* cnt  = (unsigned*)d_ws;                        // NN
    unsigned* ekey = cnt + NN;                               // NN*STRIDE (25.6 MB)
    _Float16* h    = (_Float16*)(ekey + (size_t)NN * STRIDE);// NN*NHID f16 (1.6 MB)
    _Float16* W2f  = h + (size_t)NN * NHID;                  // 86 KB
    unsigned* gBinCur = (unsigned*)(W2f + NCT * NKB * 512);  // 512 u32
    unsigned* gRecs   = gBinCur + 512;                       // NBIN*BINCAP (19.2 MB)

    const int blk = 256;
    hipMemsetAsync(gBinCur, 0, 512 * sizeof(unsigned), stream);
    scat1_kernel<<<(EB + TILE - 1) / TILE, blk, 0, stream>>>(src, rel, dst, gBinCur, gRecs);
    scat2_kernel<<<NBIN, blk, 0, stream>>>(gBinCur, gRecs, cnt, ekey);
    pack_kernel<<<(NCT * NKB * 512 + blk - 1) / blk, blk, 0, stream>>>(W2, W2f);
    layer1_kernel<<<NN / AGW, blk, 0, stream>>>(ekey, cnt, W1, b1, h);
    agg_gemm_kernel<<<NROWS / FNPB, 512, 0, stream>>>(ekey, cnt, h, W2f, b2, out);
}